// Round 12
// baseline (62.260 us; speedup 1.0000x reference)
//
#include <hip/hip_runtime.h>

typedef float f4 __attribute__((ext_vector_type(4)));

static __device__ __forceinline__ f4 vexp2(f4 a) {
  f4 r;
  r.x = __builtin_amdgcn_exp2f(a.x);
  r.y = __builtin_amdgcn_exp2f(a.y);
  r.z = __builtin_amdgcn_exp2f(a.z);
  r.w = __builtin_amdgcn_exp2f(a.w);
  return r;
}

#define LOG2E 1.4426950408889634f
#define TILE 8
#define ROWS (TILE + 3)   // 11 staged padded rows per tile

// Grid: 8(b) x 16(h-tile) x 8(channel quad) = 1024 blocks, 512 threads.
// Thread = (w = t&127, cg = t>>7) owns TWO channels c0 = cq*4+cg, c1 = c0+32
// (independent softmax chains -> ILP at every latency point, R11-proven),
// marching down TILE=8 rows with a sliding register tap window.
// R12 changes vs R11:
//  - vsq (v^2) cached in the slide for BOTH channels: e-stage 64->32
//    muls/step (R10-proven win, was dropped for register pressure).
//  - q-conv re-reads its 3 x-values from LDS (imm-offset ds_read_b32 on the
//    underused LDS pipe) instead of a 3-reg stash carried across SLIDE.
//  - em/out addressed as uniform-base[s*128 + w] to encourage saddr-form
//    memory ops (fewer VGPR address pairs).
//
// VGPR cap is 256/N for __launch_bounds__(.,N) (R3: N=8 -> 32, disaster;
// R7: N=4 -> 64, spilled; R8-R11: N=2 -> 52..104 used, no spill).
// No-max softmax both stages (R8-R11-validated: |tl|<~110 < 126, |z|<~4).
// Plain C++ vector math only (R5: inline-asm v_pk_* broke correctness).
__global__ __launch_bounds__(512, 2) void stem_kernel(
    const float* __restrict__ x,    // [8,3,128,128]
    const float* __restrict__ qwp,  // [64,3]
    const float* __restrict__ kwp,  // [64,3]
    const float* __restrict__ vwp,  // [64,3]
    const float* __restrict__ ea,   // [64,128]  (c, w)
    const float* __restrict__ eb,   // [64,128]  (c, h)
    const float* __restrict__ em,   // [64,128,128] (c, h, w)
    float* __restrict__ out)        // [8,64,128,128]
{
  __shared__ float xs[3][ROWS][132];   // 17.4 KB

  const int blk = blockIdx.x;
  const int cq = blk & 7;             // channel quad (low half)
  const int ht = (blk >> 3) & 15;     // h tile
  const int b  = blk >> 7;
  const int h0 = ht * TILE;
  const int t  = threadIdx.x;

  // ---- stage: interior cols via shift-only addressing, pads separately.
  {
    const float* xb = x + b * (3 * 128 * 128);
    for (int idx = t; idx < 3 * ROWS * 128; idx += 512) {
      int row = idx >> 7;                 // cin*ROWS + rr
      int wp2 = idx & 127;                // dest col wp2+2, source col wp2
      int cin = (row >= ROWS) + (row >= 2 * ROWS);
      int rr  = row - cin * ROWS;
      int g   = h0 - 2 + rr;              // source row (may be OOB -> 0)
      float v = 0.f;
      if ((unsigned)g < 128u) v = xb[(cin * 128 + g) * 128 + wp2];
      xs[cin][rr][wp2 + 2] = v;
    }
    if (t < 3 * ROWS * 4) {               // pad cols {0,1,130,131} = 0
      int row = t >> 2;
      int col = t & 3;
      int wp  = (col & 1) + ((col >> 1) ? 130 : 0);
      int cin = (row >= ROWS) + (row >= 2 * ROWS);
      int rr  = row - cin * ROWS;
      xs[cin][rr][wp] = 0.f;
    }
  }
  __syncthreads();

  const int w  = t & 127;
  const int cg = t >> 7;                              // wave-uniform
  const int c0 = __builtin_amdgcn_readfirstlane(cq * 4 + cg);
  const int c1 = c0 + 32;

  // wave-uniform weights -> scalar loads (SGPRs); LOG2E folded into qw
  const float kwa0 = kwp[c0 * 3], kwb0 = kwp[c0 * 3 + 1], kwc0 = kwp[c0 * 3 + 2];
  const float kwa1 = kwp[c1 * 3], kwb1 = kwp[c1 * 3 + 1], kwc1 = kwp[c1 * 3 + 2];
  const float vwa0 = vwp[c0 * 3], vwb0 = vwp[c0 * 3 + 1], vwc0 = vwp[c0 * 3 + 2];
  const float vwa1 = vwp[c1 * 3], vwb1 = vwp[c1 * 3 + 1], vwc1 = vwp[c1 * 3 + 2];
  const float qwa0 = qwp[c0 * 3] * LOG2E, qwb0 = qwp[c0 * 3 + 1] * LOG2E,
              qwc0 = qwp[c0 * 3 + 2] * LOG2E;
  const float qwa1 = qwp[c1 * 3] * LOG2E, qwb1 = qwp[c1 * 3 + 1] * LOG2E,
              qwc1 = qwp[c1 * 3 + 2] * LOG2E;

  const float ea0 = ea[c0 * 128 + w];                 // h-invariant, hoisted
  const float ea1 = ea[c1 * 128 + w];
  const float* ebp0 = eb + c0 * 128 + h0;             // uniform -> s_loads
  const float* ebp1 = eb + c1 * 128 + h0;
  // uniform bases; per-lane index [s*128 + w] -> saddr-form vmem
  const float* emb0 = em + (c0 * 128 + h0) * 128;
  const float* emb1 = em + (c1 * 128 + h0) * 128;
  float* outb0 = out + ((b * 64 + c0) * 128 + h0) * 128;
  float* outb1 = out + ((b * 64 + c1) * 128 + h0) * 128;

  // sliding tap windows for BOTH channels (+ v^2 caches)
  f4 kk0[4], vv0[4], vq0[4], kk1[4], vv1[4], vq1[4];

#define SLIDE(RR, COMP)                                        \
  do {                                                         \
    _Pragma("unroll")                                          \
    for (int j = 0; j < 4; ++j) {                              \
      float x0 = xs[0][RR][w + j];                             \
      float x1 = xs[1][RR][w + j];                             \
      float x2 = xs[2][RR][w + j];                             \
      float kn0 = kwc0 * x2 + (kwa0 * x0 + kwb0 * x1);         \
      float vn0 = vwc0 * x2 + (vwa0 * x0 + vwb0 * x1);         \
      float kn1 = kwc1 * x2 + (kwa1 * x0 + kwb1 * x1);         \
      float vn1 = vwc1 * x2 + (vwa1 * x0 + vwb1 * x1);         \
      kk0[j][COMP] = kn0; vv0[j][COMP] = vn0;                  \
      vq0[j][COMP] = vn0 * vn0;                                \
      kk1[j][COMP] = kn1; vv1[j][COMP] = vn1;                  \
      vq1[j][COMP] = vn1 * vn1;                                \
    }                                                          \
  } while (0)

  // prologue: window rows rr=0,1,2 into slots 0,1,2
  SLIDE(0, 0);
  SLIDE(1, 1);
  SLIDE(2, 2);

#pragma unroll
  for (int s = 0; s < TILE; ++s) {
    SLIDE(s + 3, ((s + 3) & 3));         // entering row -> retiring slot

    // q conv at (h0+s, w): staged row s+2, col w+2 (direct LDS re-read,
    // imm offsets off the same w*4 vaddr; LDS pipe has spare capacity)
    const float q0 = qwa0 * xs[0][s + 2][w + 2] + qwb0 * xs[1][s + 2][w + 2] +
                     qwc0 * xs[2][s + 2][w + 2];
    const float q1 = qwa1 * xs[0][s + 2][w + 2] + qwb1 * xs[1][s + 2][w + 2] +
                     qwc1 * xs[2][s + 2][w + 2];

    const float sp0 = (ea0 + ebp0[s]) * emb0[s * 128 + w] * LOG2E;
    const float sp1 = (ea1 + ebp1[s]) * emb1[s * 128 + w] * LOG2E;

    // embedding weights e = 2^(sp * vsq) via cached v^2 (16 muls/channel);
    // no max-subtraction; 1/sum_e folded into qs.
    f4 e00 = vexp2(sp0 * vq0[0]);
    f4 e01 = vexp2(sp0 * vq0[1]);
    f4 e02 = vexp2(sp0 * vq0[2]);
    f4 e03 = vexp2(sp0 * vq0[3]);
    f4 e10 = vexp2(sp1 * vq1[0]);
    f4 e11 = vexp2(sp1 * vq1[1]);
    f4 e12 = vexp2(sp1 * vq1[2]);
    f4 e13 = vexp2(sp1 * vq1[3]);

    f4 se0 = (e00 + e01) + (e02 + e03);
    f4 se1 = (e10 + e11) + (e12 + e13);
    const float sum0 = (se0.x + se0.y) + (se0.z + se0.w);
    const float sum1 = (se1.x + se1.y) + (se1.z + se1.w);
    const float qs0 = q0 * __builtin_amdgcn_rcpf(sum0);  // LOG2E already in q
    const float qs1 = q1 * __builtin_amdgcn_rcpf(sum1);

    // att: p = 2^(qs * k * e); |arg| <~ 4 -> no max-subtraction needed
    f4 p00 = vexp2((qs0 * kk0[0]) * e00);
    f4 p01 = vexp2((qs0 * kk0[1]) * e01);
    f4 p02 = vexp2((qs0 * kk0[2]) * e02);
    f4 p03 = vexp2((qs0 * kk0[3]) * e03);
    f4 p10 = vexp2((qs1 * kk1[0]) * e10);
    f4 p11 = vexp2((qs1 * kk1[1]) * e11);
    f4 p12 = vexp2((qs1 * kk1[2]) * e12);
    f4 p13 = vexp2((qs1 * kk1[3]) * e13);

    f4 ps0 = (p00 + p01) + (p02 + p03);
    f4 ps1 = (p10 + p11) + (p12 + p13);
    f4 pv0 = (p00 * vv0[0] + p01 * vv0[1]) + (p02 * vv0[2] + p03 * vv0[3]);
    f4 pv1 = (p10 * vv1[0] + p11 * vv1[1]) + (p12 * vv1[2] + p13 * vv1[3]);

    const float den0 = (ps0.x + ps0.y) + (ps0.z + ps0.w);
    const float den1 = (ps1.x + ps1.y) + (ps1.z + ps1.w);
    const float num0 = (pv0.x + pv0.y) + (pv0.z + pv0.w);
    const float num1 = (pv1.x + pv1.y) + (pv1.z + pv1.w);

    outb0[s * 128 + w] = num0 * __builtin_amdgcn_rcpf(den0);
    outb1[s * 128 + w] = num1 * __builtin_amdgcn_rcpf(den1);
  }
#undef SLIDE
}

extern "C" void kernel_launch(void* const* d_in, const int* in_sizes, int n_in,
                              void* d_out, int out_size, void* d_ws, size_t ws_size,
                              hipStream_t stream) {
  const float* x  = (const float*)d_in[0];
  const float* qw = (const float*)d_in[1];
  const float* kw = (const float*)d_in[2];
  const float* vw = (const float*)d_in[3];
  const float* ea = (const float*)d_in[4];
  const float* eb = (const float*)d_in[5];
  const float* em = (const float*)d_in[6];
  float* out = (float*)d_out;

  stem_kernel<<<dim3(8 * 16 * 8), dim3(512), 0, stream>>>(x, qw, kw, vw, ea, eb, em, out);
}

// Round 14
// 55.487 us; speedup vs baseline: 1.1221x; 1.1221x over previous
//
#include <hip/hip_runtime.h>

typedef float f4 __attribute__((ext_vector_type(4)));

static __device__ __forceinline__ f4 vexp2(f4 a) {
  f4 r;
  r.x = __builtin_amdgcn_exp2f(a.x);
  r.y = __builtin_amdgcn_exp2f(a.y);
  r.z = __builtin_amdgcn_exp2f(a.z);
  r.w = __builtin_amdgcn_exp2f(a.w);
  return r;
}

#define LOG2E 1.4426950408889634f
#define TILE 8
#define ROWS (TILE + 3)   // 11 staged padded rows per tile

// FINAL (R11 lock-in, 55.5 us proven). Grid: 8(b) x 16(h-tile) x
// 8(channel quad) = 1024 blocks, 512 threads. Thread = (w = t&127,
// cg = t>>7) owns TWO channels c0 = cq*4+cg, c1 = c0+32: two fully
// independent softmax chains give ILP at every latency point (exp, rcp,
// sum trees) and share one x-window (12 LDS reads serve both).
// Sliding register tap window marches down TILE=8 rows; row loop fully
// unrolled so LDS reads are imm-offset ds_read_b32 off one w*4 vaddr.
//
// Session lessons encoded here:
//  - VGPR cap is 256/N for __launch_bounds__(.,N): N=8 -> 32 (R3
//    disaster), N=4 -> 64 (R7 spill), N=2 -> 128 (R8-R12 safe).
//  - In the 65-128-reg band, live registers cost more than instructions
//    (R12: vsq cache = -32 muls, +32 live regs -> -12% regression).
//  - Inline-asm v_pk_*_f32 is broken on this toolchain path (R5 absmax
//    0.18, R13 NaN with explicit op_sel_hi). Plain C++ vectors only.
//  - No-max softmax is safe BOTH stages (R8-R12: |tl|<~110 < 126, |z|<~4;
//    absmax identical to max-subtracted variants).
//  - The e-exp -> sum -> rcp -> p-exp chain is algebraically irreducible
//    (normalized embedding sits inside the second exponent).
__global__ __launch_bounds__(512, 2) void stem_kernel(
    const float* __restrict__ x,    // [8,3,128,128]
    const float* __restrict__ qwp,  // [64,3]
    const float* __restrict__ kwp,  // [64,3]
    const float* __restrict__ vwp,  // [64,3]
    const float* __restrict__ ea,   // [64,128]  (c, w)
    const float* __restrict__ eb,   // [64,128]  (c, h)
    const float* __restrict__ em,   // [64,128,128] (c, h, w)
    float* __restrict__ out)        // [8,64,128,128]
{
  __shared__ float xs[3][ROWS][132];   // 17.4 KB

  const int blk = blockIdx.x;
  const int cq = blk & 7;             // channel quad (low half)
  const int ht = (blk >> 3) & 15;     // h tile
  const int b  = blk >> 7;
  const int h0 = ht * TILE;
  const int t  = threadIdx.x;

  // ---- stage: interior cols via shift-only addressing, pads separately.
  {
    const float* xb = x + b * (3 * 128 * 128);
    for (int idx = t; idx < 3 * ROWS * 128; idx += 512) {
      int row = idx >> 7;                 // cin*ROWS + rr
      int wp2 = idx & 127;                // dest col wp2+2, source col wp2
      int cin = (row >= ROWS) + (row >= 2 * ROWS);
      int rr  = row - cin * ROWS;
      int g   = h0 - 2 + rr;              // source row (may be OOB -> 0)
      float v = 0.f;
      if ((unsigned)g < 128u) v = xb[(cin * 128 + g) * 128 + wp2];
      xs[cin][rr][wp2 + 2] = v;
    }
    if (t < 3 * ROWS * 4) {               // pad cols {0,1,130,131} = 0
      int row = t >> 2;
      int col = t & 3;
      int wp  = (col & 1) + ((col >> 1) ? 130 : 0);
      int cin = (row >= ROWS) + (row >= 2 * ROWS);
      int rr  = row - cin * ROWS;
      xs[cin][rr][wp] = 0.f;
    }
  }
  __syncthreads();

  const int w  = t & 127;
  const int cg = t >> 7;                              // wave-uniform
  const int c0 = __builtin_amdgcn_readfirstlane(cq * 4 + cg);
  const int c1 = c0 + 32;

  // wave-uniform weights -> scalar loads (SGPRs); LOG2E folded into qw
  const float kwa0 = kwp[c0 * 3], kwb0 = kwp[c0 * 3 + 1], kwc0 = kwp[c0 * 3 + 2];
  const float kwa1 = kwp[c1 * 3], kwb1 = kwp[c1 * 3 + 1], kwc1 = kwp[c1 * 3 + 2];
  const float vwa0 = vwp[c0 * 3], vwb0 = vwp[c0 * 3 + 1], vwc0 = vwp[c0 * 3 + 2];
  const float vwa1 = vwp[c1 * 3], vwb1 = vwp[c1 * 3 + 1], vwc1 = vwp[c1 * 3 + 2];
  const float qwa0 = qwp[c0 * 3] * LOG2E, qwb0 = qwp[c0 * 3 + 1] * LOG2E,
              qwc0 = qwp[c0 * 3 + 2] * LOG2E;
  const float qwa1 = qwp[c1 * 3] * LOG2E, qwb1 = qwp[c1 * 3 + 1] * LOG2E,
              qwc1 = qwp[c1 * 3 + 2] * LOG2E;

  const float ea0 = ea[c0 * 128 + w];                 // h-invariant, hoisted
  const float ea1 = ea[c1 * 128 + w];
  const float* ebp0 = eb + c0 * 128 + h0;             // uniform -> s_loads
  const float* ebp1 = eb + c1 * 128 + h0;
  const float* emp0 = em + (c0 * 128 + h0) * 128 + w;
  const float* emp1 = em + (c1 * 128 + h0) * 128 + w;
  float* outp0 = out + ((b * 64 + c0) * 128 + h0) * 128 + w;
  float* outp1 = out + ((b * 64 + c1) * 128 + h0) * 128 + w;

  // sliding tap windows for BOTH channels + shared q-conv stash (col w+2
  // of the last-slid row = the q inputs for the NEXT step)
  f4 kk0[4], vv0[4], kk1[4], vv1[4];
  float qx0, qx1, qx2;

#define SLIDE(RR, COMP)                                        \
  do {                                                         \
    _Pragma("unroll")                                          \
    for (int j = 0; j < 4; ++j) {                              \
      float x0 = xs[0][RR][w + j];                             \
      float x1 = xs[1][RR][w + j];                             \
      float x2 = xs[2][RR][w + j];                             \
      kk0[j][COMP] = kwc0 * x2 + (kwa0 * x0 + kwb0 * x1);      \
      vv0[j][COMP] = vwc0 * x2 + (vwa0 * x0 + vwb0 * x1);      \
      kk1[j][COMP] = kwc1 * x2 + (kwa1 * x0 + kwb1 * x1);      \
      vv1[j][COMP] = vwc1 * x2 + (vwa1 * x0 + vwb1 * x1);      \
      if (j == 2) { qx0 = x0; qx1 = x1; qx2 = x2; }            \
    }                                                          \
  } while (0)

  // prologue: window rows rr=0,1,2 into slots 0,1,2; stash = row 2 (s=0 q row)
  SLIDE(0, 0);
  SLIDE(1, 1);
  SLIDE(2, 2);

#pragma unroll
  for (int s = 0; s < TILE; ++s) {
    // q convs (pre-scaled by LOG2E) from the stash, BEFORE SLIDE clobbers it
    const float q0 = qwa0 * qx0 + qwb0 * qx1 + qwc0 * qx2;
    const float q1 = qwa1 * qx0 + qwb1 * qx1 + qwc1 * qx2;

    SLIDE(s + 3, ((s + 3) & 3));         // entering row -> retiring slot

    const float sp0 = (ea0 + ebp0[s]) * emp0[s * 128] * LOG2E;
    const float sp1 = (ea1 + ebp1[s]) * emp1[s * 128] * LOG2E;

    // embedding weights e = 2^(sp * v^2), no max-subtraction; the two
    // channels' exp chains are independent -> back-to-back issue.
    f4 e00 = vexp2((sp0 * vv0[0]) * vv0[0]);
    f4 e01 = vexp2((sp0 * vv0[1]) * vv0[1]);
    f4 e02 = vexp2((sp0 * vv0[2]) * vv0[2]);
    f4 e03 = vexp2((sp0 * vv0[3]) * vv0[3]);
    f4 e10 = vexp2((sp1 * vv1[0]) * vv1[0]);
    f4 e11 = vexp2((sp1 * vv1[1]) * vv1[1]);
    f4 e12 = vexp2((sp1 * vv1[2]) * vv1[2]);
    f4 e13 = vexp2((sp1 * vv1[3]) * vv1[3]);

    f4 se0 = (e00 + e01) + (e02 + e03);
    f4 se1 = (e10 + e11) + (e12 + e13);
    const float sum0 = (se0.x + se0.y) + (se0.z + se0.w);
    const float sum1 = (se1.x + se1.y) + (se1.z + se1.w);
    const float qs0 = q0 * __builtin_amdgcn_rcpf(sum0);  // LOG2E already in q
    const float qs1 = q1 * __builtin_amdgcn_rcpf(sum1);

    // att: p = 2^(qs * k * e); |arg| <~ 4 -> no max-subtraction needed
    f4 p00 = vexp2((qs0 * kk0[0]) * e00);
    f4 p01 = vexp2((qs0 * kk0[1]) * e01);
    f4 p02 = vexp2((qs0 * kk0[2]) * e02);
    f4 p03 = vexp2((qs0 * kk0[3]) * e03);
    f4 p10 = vexp2((qs1 * kk1[0]) * e10);
    f4 p11 = vexp2((qs1 * kk1[1]) * e11);
    f4 p12 = vexp2((qs1 * kk1[2]) * e12);
    f4 p13 = vexp2((qs1 * kk1[3]) * e13);

    f4 ps0 = (p00 + p01) + (p02 + p03);
    f4 ps1 = (p10 + p11) + (p12 + p13);
    f4 pv0 = (p00 * vv0[0] + p01 * vv0[1]) + (p02 * vv0[2] + p03 * vv0[3]);
    f4 pv1 = (p10 * vv1[0] + p11 * vv1[1]) + (p12 * vv1[2] + p13 * vv1[3]);

    const float den0 = (ps0.x + ps0.y) + (ps0.z + ps0.w);
    const float den1 = (ps1.x + ps1.y) + (ps1.z + ps1.w);
    const float num0 = (pv0.x + pv0.y) + (pv0.z + pv0.w);
    const float num1 = (pv1.x + pv1.y) + (pv1.z + pv1.w);

    outp0[s * 128] = num0 * __builtin_amdgcn_rcpf(den0);
    outp1[s * 128] = num1 * __builtin_amdgcn_rcpf(den1);
  }
#undef SLIDE
}

extern "C" void kernel_launch(void* const* d_in, const int* in_sizes, int n_in,
                              void* d_out, int out_size, void* d_ws, size_t ws_size,
                              hipStream_t stream) {
  const float* x  = (const float*)d_in[0];
  const float* qw = (const float*)d_in[1];
  const float* kw = (const float*)d_in[2];
  const float* vw = (const float*)d_in[3];
  const float* ea = (const float*)d_in[4];
  const float* eb = (const float*)d_in[5];
  const float* em = (const float*)d_in[6];
  float* out = (float*)d_out;

  stem_kernel<<<dim3(8 * 16 * 8), dim3(512), 0, stream>>>(x, qw, kw, vw, ea, eb, em, out);
}